// Round 1
// baseline (735.339 us; speedup 1.0000x reference)
//
#include <hip/hip_runtime.h>
#include <hip/hip_bf16.h>

// Problem constants (fixed by the reference)
#define HD   4096      // hidden
#define ID   14336     // intermediate
#define NB   64        // batch
#define NLUTN 4096
#define KSPLIT 4       // down-proj K split

typedef __attribute__((ext_vector_type(8))) short short8;   // 8 x bf16 bits = 4 VGPRs
typedef __attribute__((ext_vector_type(4))) float f32x4;    // MFMA accumulator

__device__ __forceinline__ unsigned short f2bf(float f) {
  __hip_bfloat16 h = __float2bfloat16(f);
  return __builtin_bit_cast(unsigned short, h);
}

// ---------------------------------------------------------------------------
// prep: x'_g[b][h] = bf16(x[b][h]*gsr[h]), x'_u likewise. 64*4096 elements.
// grid 256 x 256 threads, 4 elements (one float4) per thread.
// ---------------------------------------------------------------------------
__global__ __launch_bounds__(256) void prep_kernel(
    const float* __restrict__ x, const float* __restrict__ gsr,
    const float* __restrict__ usr,
    unsigned short* __restrict__ xg, unsigned short* __restrict__ xu)
{
  int t = blockIdx.x * 256 + threadIdx.x;          // 0..65535 float4s
  float4 xv = ((const float4*)x)[t];
  int hs = t & (HD/4 - 1);                         // float4 index within row
  float4 g = ((const float4*)gsr)[hs];
  float4 u = ((const float4*)usr)[hs];
  ushort4 og = make_ushort4(f2bf(xv.x*g.x), f2bf(xv.y*g.y), f2bf(xv.z*g.z), f2bf(xv.w*g.w));
  ushort4 ou = make_ushort4(f2bf(xv.x*u.x), f2bf(xv.y*u.y), f2bf(xv.z*u.z), f2bf(xv.w*u.w));
  ((ushort4*)xg)[t] = og;
  ((ushort4*)xu)[t] = ou;
}

// ---------------------------------------------------------------------------
// gate+up: one wave (64 thr) per 16-row I-strip. N=64 batches, K=4096.
// A-frag dequant: global int32 walk loads + LDS bf16-LUT gather.
// Epilogue: hidden[b][i] = silu(0.02*gsl*g) * (0.02*usl*u) * dsr  -> bf16 ws.
// grid = ID/16 = 896 blocks.
// ---------------------------------------------------------------------------
__global__ __launch_bounds__(64) void gate_up_kernel(
    const int* __restrict__ gw, const int* __restrict__ uw,
    const float* __restrict__ lutg_f, const float* __restrict__ lutu_f,
    const unsigned short* __restrict__ xg, const unsigned short* __restrict__ xu,
    const float* __restrict__ gsl, const float* __restrict__ usl,
    const float* __restrict__ dsr,
    unsigned short* __restrict__ hidden)
{
  __shared__ unsigned short lutg[NLUTN];
  __shared__ unsigned short lutu[NLUTN];
  const int tid = threadIdx.x;

  // Stage LUTs as bf16 bits (8 KB each)
  #pragma unroll
  for (int i = tid; i < NLUTN/4; i += 64) {
    float4 g = ((const float4*)lutg_f)[i];
    float4 u = ((const float4*)lutu_f)[i];
    ((ushort4*)lutg)[i] = make_ushort4(f2bf(g.x), f2bf(g.y), f2bf(g.z), f2bf(g.w));
    ((ushort4*)lutu)[i] = make_ushort4(f2bf(u.x), f2bf(u.y), f2bf(u.z), f2bf(u.w));
  }
  __syncthreads();

  const int col  = tid & 15;   // A: row-within-strip; B: batch-within-tile; D: batch col
  const int quad = tid >> 4;
  const int m0   = blockIdx.x * 16;

  const int* gp = gw + (size_t)(m0 + col) * HD + quad * 8;
  const int* up = uw + (size_t)(m0 + col) * HD + quad * 8;
  const unsigned short* xgp[4];
  const unsigned short* xup[4];
  #pragma unroll
  for (int t = 0; t < 4; ++t) {
    xgp[t] = xg + (size_t)(t*16 + col) * HD + quad * 8;
    xup[t] = xu + (size_t)(t*16 + col) * HD + quad * 8;
  }

  const f32x4 z = {0.f, 0.f, 0.f, 0.f};
  f32x4 accg[4] = {z, z, z, z};
  f32x4 accu[4] = {z, z, z, z};

  for (int k0 = 0; k0 < HD; k0 += 32) {
    int4 ga = *(const int4*)(gp + k0);
    int4 gb = *(const int4*)(gp + k0 + 4);
    int4 ua = *(const int4*)(up + k0);
    int4 ub = *(const int4*)(up + k0 + 4);

    short8 afg, afu;
    afg[0] = (short)lutg[ga.x]; afg[1] = (short)lutg[ga.y];
    afg[2] = (short)lutg[ga.z]; afg[3] = (short)lutg[ga.w];
    afg[4] = (short)lutg[gb.x]; afg[5] = (short)lutg[gb.y];
    afg[6] = (short)lutg[gb.z]; afg[7] = (short)lutg[gb.w];
    afu[0] = (short)lutu[ua.x]; afu[1] = (short)lutu[ua.y];
    afu[2] = (short)lutu[ua.z]; afu[3] = (short)lutu[ua.w];
    afu[4] = (short)lutu[ub.x]; afu[5] = (short)lutu[ub.y];
    afu[6] = (short)lutu[ub.z]; afu[7] = (short)lutu[ub.w];

    #pragma unroll
    for (int t = 0; t < 4; ++t) {
      short8 bg = __builtin_bit_cast(short8, *(const int4*)(xgp[t] + k0));
      short8 bu = __builtin_bit_cast(short8, *(const int4*)(xup[t] + k0));
      accg[t] = __builtin_amdgcn_mfma_f32_16x16x32_bf16(afg, bg, accg[t], 0, 0, 0);
      accu[t] = __builtin_amdgcn_mfma_f32_16x16x32_bf16(afu, bu, accu[t], 0, 0, 0);
    }
  }

  // Epilogue. D mapping: col = lane&15 (batch), row = quad*4 + reg (i).
  const int mrow = m0 + quad * 4;
  float sg[4], su[4], sd[4];
  #pragma unroll
  for (int r = 0; r < 4; ++r) {
    sg[r] = 0.02f * gsl[mrow + r];
    su[r] = 0.02f * usl[mrow + r];
    sd[r] = dsr[mrow + r];
  }
  #pragma unroll
  for (int t = 0; t < 4; ++t) {
    int b = t*16 + col;
    ushort4 hv;
    float g0 = accg[t][0] * sg[0], u0 = accu[t][0] * su[0];
    float g1 = accg[t][1] * sg[1], u1 = accu[t][1] * su[1];
    float g2 = accg[t][2] * sg[2], u2 = accu[t][2] * su[2];
    float g3 = accg[t][3] * sg[3], u3 = accu[t][3] * su[3];
    hv.x = f2bf((g0 / (1.f + __expf(-g0))) * u0 * sd[0]);
    hv.y = f2bf((g1 / (1.f + __expf(-g1))) * u1 * sd[1]);
    hv.z = f2bf((g2 / (1.f + __expf(-g2))) * u2 * sd[2]);
    hv.w = f2bf((g3 / (1.f + __expf(-g3))) * u3 * sd[3]);
    *((ushort4*)(hidden + (size_t)b * ID + mrow)) = hv;
  }
}

// ---------------------------------------------------------------------------
// down: out[b][h] = 0.02*dsl[h] * sum_i hidden[b][i]*lut_d[dw[h,i]]
// grid (HD/16, KSPLIT) = (256, 4) single-wave blocks; f32 atomicAdd epilogue.
// ---------------------------------------------------------------------------
__global__ __launch_bounds__(64) void down_kernel(
    const int* __restrict__ dw, const float* __restrict__ lutd_f,
    const unsigned short* __restrict__ hidden,
    const float* __restrict__ dsl,
    float* __restrict__ out)
{
  __shared__ unsigned short lutd[NLUTN];
  const int tid = threadIdx.x;
  #pragma unroll
  for (int i = tid; i < NLUTN/4; i += 64) {
    float4 d = ((const float4*)lutd_f)[i];
    ((ushort4*)lutd)[i] = make_ushort4(f2bf(d.x), f2bf(d.y), f2bf(d.z), f2bf(d.w));
  }
  __syncthreads();

  const int col  = tid & 15;
  const int quad = tid >> 4;
  const int m0   = blockIdx.x * 16;          // h strip
  const int kbeg = blockIdx.y * (ID / KSPLIT);
  const int kend = kbeg + (ID / KSPLIT);

  const int* dp = dw + (size_t)(m0 + col) * ID + quad * 8;
  const unsigned short* hp[4];
  #pragma unroll
  for (int t = 0; t < 4; ++t)
    hp[t] = hidden + (size_t)(t*16 + col) * ID + quad * 8;

  const f32x4 z = {0.f, 0.f, 0.f, 0.f};
  f32x4 acc[4] = {z, z, z, z};

  for (int k0 = kbeg; k0 < kend; k0 += 32) {
    int4 da = *(const int4*)(dp + k0);
    int4 db = *(const int4*)(dp + k0 + 4);
    short8 af;
    af[0] = (short)lutd[da.x]; af[1] = (short)lutd[da.y];
    af[2] = (short)lutd[da.z]; af[3] = (short)lutd[da.w];
    af[4] = (short)lutd[db.x]; af[5] = (short)lutd[db.y];
    af[6] = (short)lutd[db.z]; af[7] = (short)lutd[db.w];
    #pragma unroll
    for (int t = 0; t < 4; ++t) {
      short8 bh = __builtin_bit_cast(short8, *(const int4*)(hp[t] + k0));
      acc[t] = __builtin_amdgcn_mfma_f32_16x16x32_bf16(af, bh, acc[t], 0, 0, 0);
    }
  }

  const int mrow = m0 + quad * 4;
  float sc[4];
  #pragma unroll
  for (int r = 0; r < 4; ++r) sc[r] = 0.02f * dsl[mrow + r];
  #pragma unroll
  for (int t = 0; t < 4; ++t) {
    int b = t*16 + col;
    #pragma unroll
    for (int r = 0; r < 4; ++r)
      atomicAdd(&out[(size_t)b * HD + mrow + r], acc[t][r] * sc[r]);
  }
}

// ---------------------------------------------------------------------------
extern "C" void kernel_launch(void* const* d_in, const int* in_sizes, int n_in,
                              void* d_out, int out_size, void* d_ws, size_t ws_size,
                              hipStream_t stream) {
  const float* x    = (const float*)d_in[0];
  const float* lutg = (const float*)d_in[1];
  const float* lutu = (const float*)d_in[2];
  const float* lutd = (const float*)d_in[3];
  const int*   gw   = (const int*)d_in[4];
  const int*   uw   = (const int*)d_in[5];
  const int*   dw   = (const int*)d_in[6];
  const float* gsl  = (const float*)d_in[7];
  const float* gsr  = (const float*)d_in[8];
  const float* usl  = (const float*)d_in[9];
  const float* usr  = (const float*)d_in[10];
  const float* dsl  = (const float*)d_in[11];
  const float* dsr  = (const float*)d_in[12];
  float* out = (float*)d_out;

  // ws layout: xg (512KB) | xu (512KB) | hidden (1.75MB)  -> ~2.75 MB total
  unsigned short* xg     = (unsigned short*)d_ws;
  unsigned short* xu     = xg + (size_t)NB * HD;
  unsigned short* hidden = xu + (size_t)NB * HD;

  hipMemsetAsync(d_out, 0, (size_t)NB * HD * sizeof(float), stream);
  prep_kernel<<<(NB*HD/4 + 255)/256, 256, 0, stream>>>(x, gsr, usr, xg, xu);
  gate_up_kernel<<<ID/16, 64, 0, stream>>>(gw, uw, lutg, lutu, xg, xu,
                                           gsl, usl, dsr, hidden);
  down_kernel<<<dim3(HD/16, KSPLIT), 64, 0, stream>>>(dw, lutd, hidden, dsl, out);
}